// Round 2
// baseline (917.977 us; speedup 1.0000x reference)
//
#include <hip/hip_runtime.h>
#include <math.h>

#define B_  64
#define N_  1024
#define H_  64
#define IN_ 512
#define G4  256   // 4*H
#define CH  64    // xg LDS chunk length (steps)

// ---------------------------------------------------------------------------
// Kernel A: xg[b][n][g] = sum_k x[b][n][k] * W_ih[g][k] + b_ih[g] + b_hh[g]
// 128x128 tile, BK=32, 256 threads, 8x8 microtile. m = n*64 + b ordering for
// the tile walk; output written at [b][n][g] so the scan's slice is contiguous.
// ---------------------------------------------------------------------------
__global__ __launch_bounds__(256) void gemm_xg_kernel(
    const float* __restrict__ x,     // [64][1024][512]
    const float* __restrict__ Wih,   // [256][512]
    const float* __restrict__ bih,
    const float* __restrict__ bhh,
    float* __restrict__ xg)          // [64][1024][256]
{
    __shared__ float As[32][132];    // [k][m_local], +4 pad
    __shared__ float Bs[32][132];    // [k][g_local]

    const int tid = threadIdx.x;
    const int g0  = blockIdx.x * 128;   // 2 g-tiles
    const int m0  = blockIdx.y * 128;   // 512 m-tiles

    const int tx = tid & 15;            // g microtile (8 cols: tx*4, 64+tx*4)
    const int ty = tid >> 4;            // m microtile (8 rows: ty*4, 64+ty*4)

    const int r8 = tid >> 3;            // 0..31 staging row base
    const int kq = tid & 7;             // 0..7 k-quad (128 B per row)

    float acc[8][8];
    #pragma unroll
    for (int i = 0; i < 8; ++i)
        #pragma unroll
        for (int j = 0; j < 8; ++j) acc[i][j] = 0.f;

    for (int k0 = 0; k0 < IN_; k0 += 32) {
        #pragma unroll
        for (int it = 0; it < 4; ++it) {
            const int row = r8 + 32 * it;            // 0..127
            const int m   = m0 + row;
            const int bb  = m & 63;
            const int nn  = m >> 6;
            const float4 v = *(const float4*)&x[((size_t)bb * N_ + nn) * IN_ + k0 + kq * 4];
            As[kq * 4 + 0][row] = v.x;
            As[kq * 4 + 1][row] = v.y;
            As[kq * 4 + 2][row] = v.z;
            As[kq * 4 + 3][row] = v.w;
        }
        #pragma unroll
        for (int it = 0; it < 4; ++it) {
            const int row = r8 + 32 * it;
            const float4 v = *(const float4*)&Wih[(size_t)(g0 + row) * IN_ + k0 + kq * 4];
            Bs[kq * 4 + 0][row] = v.x;
            Bs[kq * 4 + 1][row] = v.y;
            Bs[kq * 4 + 2][row] = v.z;
            Bs[kq * 4 + 3][row] = v.w;
        }
        __syncthreads();

        #pragma unroll
        for (int k = 0; k < 32; ++k) {
            const float4 a0 = *(const float4*)&As[k][ty * 4];
            const float4 a1 = *(const float4*)&As[k][64 + ty * 4];
            const float4 b0 = *(const float4*)&Bs[k][tx * 4];
            const float4 b1 = *(const float4*)&Bs[k][64 + tx * 4];
            const float ar[8] = {a0.x, a0.y, a0.z, a0.w, a1.x, a1.y, a1.z, a1.w};
            const float br[8] = {b0.x, b0.y, b0.z, b0.w, b1.x, b1.y, b1.z, b1.w};
            #pragma unroll
            for (int i = 0; i < 8; ++i)
                #pragma unroll
                for (int j = 0; j < 8; ++j)
                    acc[i][j] = fmaf(ar[i], br[j], acc[i][j]);
        }
        __syncthreads();
    }

    float bias[8];
    #pragma unroll
    for (int j = 0; j < 4; ++j) {
        bias[j]     = bih[g0 + tx * 4 + j]      + bhh[g0 + tx * 4 + j];
        bias[4 + j] = bih[g0 + 64 + tx * 4 + j] + bhh[g0 + 64 + tx * 4 + j];
    }

    #pragma unroll
    for (int i = 0; i < 8; ++i) {
        const int row = (i < 4) ? (ty * 4 + i) : (64 + ty * 4 + i - 4);
        const int m   = m0 + row;
        const size_t base = ((size_t)(m & 63) * N_ + (m >> 6)) * G4;
        float4 o0, o1;
        o0.x = acc[i][0] + bias[0]; o0.y = acc[i][1] + bias[1];
        o0.z = acc[i][2] + bias[2]; o0.w = acc[i][3] + bias[3];
        o1.x = acc[i][4] + bias[4]; o1.y = acc[i][5] + bias[5];
        o1.z = acc[i][6] + bias[6]; o1.w = acc[i][7] + bias[7];
        *(float4*)&xg[base + g0 + tx * 4]      = o0;
        *(float4*)&xg[base + g0 + 64 + tx * 4] = o1;
    }
}

// ---------------------------------------------------------------------------
// Kernel B: recurrent scan, 64 blocks x 256 threads, ONE barrier per step.
//  - xg chunk-staged into LDS via global_load_lds (double-buffered, CH steps)
//  - c/h update replicated on all 4 waves; h_sh[w] is wave-private (no barrier)
//  - gates double-buffered across the single barrier
//  - out store rotated across waves (n%4==w) so store-acks retire off-path
// ---------------------------------------------------------------------------
__device__ __forceinline__ void load_lds_16B(const float* g, float* lds) {
    __builtin_amdgcn_global_load_lds(
        (const __attribute__((address_space(1))) unsigned int*)g,
        (__attribute__((address_space(3))) unsigned int*)lds,
        16, 0, 0);
}

__global__ __launch_bounds__(256) void lstm_scan_kernel(
    const float* __restrict__ xg,    // [B][N][256]
    const float* __restrict__ Whh,   // [256][64]
    float* __restrict__ out)         // [B][N][64]
{
    const int t  = threadIdx.x;
    const int w  = t >> 6;      // wave 0..3
    const int l  = t & 63;      // lane
    const int bb = blockIdx.x;

    __shared__ float xg_sh[2][CH][G4];   // 128 KiB
    __shared__ float h_sh[4][64];        // wave-private h copies
    __shared__ float gate_sh[2][G4];     // double-buffered gates

    // W_hh row t -> 64 VGPRs
    float4 w4[16];
    #pragma unroll
    for (int q = 0; q < 16; ++q)
        w4[q] = *(const float4*)&Whh[(size_t)t * H_ + q * 4];

    const float* xg_b = xg + (size_t)bb * N_ * G4;

    // prologue: stage chunk 0 into buf 0 (wave w loads rows w, w+4, ...)
    #pragma unroll
    for (int jj = 0; jj < CH / 4; ++jj) {
        const int j = w + 4 * jj;
        load_lds_16B(xg_b + (size_t)j * G4 + l * 4, &xg_sh[0][j][0]);
    }
    h_sh[w][l] = 0.f;
    float c = 0.f;
    __syncthreads();   // drains vmcnt -> chunk 0 ready; h init visible (own wave)

    int gbuf = 0;
    for (int n = 0; n < N_; ++n) {
        const int s    = n & (CH - 1);
        const int cbuf = (n >> 6) & 1;

        // stage next chunk at chunk boundary (drained at this step's barrier)
        if (s == 0 && n + CH < N_) {
            #pragma unroll
            for (int jj = 0; jj < CH / 4; ++jj) {
                const int j = w + 4 * jj;
                load_lds_16B(xg_b + (size_t)(n + CH + j) * G4 + l * 4,
                             &xg_sh[cbuf ^ 1][j][0]);
            }
        }

        // ---- phase 1: gate pre-activation (4 independent FMA chains) ----
        float a0 = xg_sh[cbuf][s][t], a1 = 0.f, a2 = 0.f, a3 = 0.f;
        #pragma unroll
        for (int q = 0; q < 4; ++q) {
            const float4 h0 = *(const float4*)&h_sh[w][q * 16 + 0];
            const float4 h1 = *(const float4*)&h_sh[w][q * 16 + 4];
            const float4 h2 = *(const float4*)&h_sh[w][q * 16 + 8];
            const float4 h3 = *(const float4*)&h_sh[w][q * 16 + 12];
            const float4 wa = w4[q * 4 + 0];
            const float4 wb = w4[q * 4 + 1];
            const float4 wc = w4[q * 4 + 2];
            const float4 wd = w4[q * 4 + 3];
            a0 = fmaf(wa.x, h0.x, a0); a0 = fmaf(wa.y, h0.y, a0);
            a0 = fmaf(wa.z, h0.z, a0); a0 = fmaf(wa.w, h0.w, a0);
            a1 = fmaf(wb.x, h1.x, a1); a1 = fmaf(wb.y, h1.y, a1);
            a1 = fmaf(wb.z, h1.z, a1); a1 = fmaf(wb.w, h1.w, a1);
            a2 = fmaf(wc.x, h2.x, a2); a2 = fmaf(wc.y, h2.y, a2);
            a2 = fmaf(wc.z, h2.z, a2); a2 = fmaf(wc.w, h2.w, a2);
            a3 = fmaf(wd.x, h3.x, a3); a3 = fmaf(wd.y, h3.y, a3);
            a3 = fmaf(wd.z, h3.z, a3); a3 = fmaf(wd.w, h3.w, a3);
        }
        const float accv = (a0 + a1) + (a2 + a3);

        // activation: waves 0,1,3 sigmoid; wave 2 tanh (wave-uniform branch)
        float v;
        if (t < 128 || t >= 192) {
            v = __builtin_amdgcn_rcpf(1.f + __expf(-accv));
        } else {
            v = 1.f - 2.f * __builtin_amdgcn_rcpf(1.f + __expf(2.f * accv));
        }
        gate_sh[gbuf][t] = v;
        __syncthreads();   // the ONLY barrier per step

        // ---- phase 2: c/h update, replicated on every wave ----
        const float gi = gate_sh[gbuf][l];
        const float gf = gate_sh[gbuf][64 + l];
        const float gg = gate_sh[gbuf][128 + l];
        const float go = gate_sh[gbuf][192 + l];
        c = fmaf(gf, c, gi * gg);
        const float th = 1.f - 2.f * __builtin_amdgcn_rcpf(1.f + __expf(2.f * c));
        const float h  = go * th;
        h_sh[w][l] = h;                       // wave-private: no barrier needed
        if ((n & 3) == w)                     // rotate store duty across waves
            out[((size_t)bb * N_ + n) * H_ + l] = h;
        gbuf ^= 1;
    }
}

extern "C" void kernel_launch(void* const* d_in, const int* in_sizes, int n_in,
                              void* d_out, int out_size, void* d_ws, size_t ws_size,
                              hipStream_t stream)
{
    const float* x   = (const float*)d_in[0];
    const float* Wih = (const float*)d_in[1];
    const float* Whh = (const float*)d_in[2];
    const float* bih = (const float*)d_in[3];
    const float* bhh = (const float*)d_in[4];
    float* out = (float*)d_out;
    float* xg  = (float*)d_ws;   // 64 MiB scratch, layout [B][N][256]

    dim3 ggrid(2, 512);   // (g-tiles, m-tiles), 128x128 tiles
    gemm_xg_kernel<<<ggrid, 256, 0, stream>>>(x, Wih, bih, bhh, xg);
    lstm_scan_kernel<<<64, 256, 0, stream>>>(xg, Whh, out);
}